// Round 5
// baseline (735.530 us; speedup 1.0000x reference)
//
#include <hip/hip_runtime.h>
#include <math.h>

#define D_IN 16
#define D    64
#define H    128
#define EPSL 1e-5f
#define NPB  64        // nodes per bucket (CSR build)
#define NPB_SH 6

// =======================================================================
// Bucketed CSR build. Old path (k_hist + 3-kernel scan + k_fill) had 17x
// write amplification: each node's CSR segment is ~1 cache line, written
// 4B at a time from random CUs across 8 non-coherent XCD L2s -> one
// partial-line writeback per edge (55.7MB for 3.2MB of data).
// New path: bucket by dst>>6, stage (src,dst) into contiguous per-bucket
// regions (sequential tails), then one block per bucket builds off+csr in
// a private ~4KB window (full-line evictions, single XCD).
// =======================================================================

__global__ void k_zero(int* __restrict__ p, int n)
{
    int i = blockIdx.x * blockDim.x + threadIdx.x;
    if (i < n) p[i] = 0;
}

__global__ void k_bhist(const int* __restrict__ dst, int* __restrict__ bcnt, int E)
{
    int i = blockIdx.x * blockDim.x + threadIdx.x;
    if (i < E) atomicAdd(&bcnt[dst[i] >> NPB_SH], 1);
}

// exclusive scan of bcnt[0..B) -> bbase[0..B), single block, chunked
__global__ void k_bscan(const int* __restrict__ bcnt, int* __restrict__ bbase, int B)
{
    __shared__ int sm[1024];
    __shared__ int carry_s;
    int t = threadIdx.x;
    if (t == 0) carry_s = 0;
    __syncthreads();
    for (int c0 = 0; c0 < B; c0 += 1024) {
        int v = (c0 + t < B) ? bcnt[c0 + t] : 0;
        sm[t] = v;
        __syncthreads();
        for (int d2 = 1; d2 < 1024; d2 <<= 1) {
            int u = (t >= d2) ? sm[t - d2] : 0;
            __syncthreads();
            sm[t] += u;
            __syncthreads();
        }
        int carry = carry_s;
        if (c0 + t < B) bbase[c0 + t] = carry + sm[t] - v;   // exclusive
        __syncthreads();
        if (t == 1023) carry_s = carry + sm[1023];
        __syncthreads();
    }
}

__global__ void k_stage(const int* __restrict__ src, const int* __restrict__ dst,
                        const int* __restrict__ bbase, int* __restrict__ btail,
                        int2* __restrict__ stage, int E)
{
    int i = blockIdx.x * blockDim.x + threadIdx.x;
    if (i < E) {
        int d = dst[i];
        int b = d >> NPB_SH;
        int t = atomicAdd(&btail[b], 1);
        stage[bbase[b] + t] = make_int2(src[i], d);
    }
}

// one block per bucket: LDS count -> LDS scan -> off + csr
__global__ __launch_bounds__(256) void k_build(const int2* __restrict__ stage,
                                               const int* __restrict__ bbase,
                                               int* __restrict__ off,
                                               int* __restrict__ csr,
                                               int N, int E, int B)
{
    __shared__ int lcnt[NPB];
    __shared__ int lofs[NPB];
    int b   = blockIdx.x;
    int lo  = b << NPB_SH;
    int hi  = min(lo + NPB, N);
    int nn  = hi - lo;
    int base = bbase[b];
    int end  = (b + 1 < B) ? bbase[b + 1] : E;
    int t = threadIdx.x;

    if (t < nn) lcnt[t] = 0;
    __syncthreads();
    for (int e = base + t; e < end; e += 256)
        atomicAdd(&lcnt[stage[e].y - lo], 1);
    __syncthreads();
    if (t == 0) {
        int run = 0;
        for (int i = 0; i < nn; ++i) { lofs[i] = run; run += lcnt[i]; }
    }
    __syncthreads();
    if (t < nn) { off[lo + t] = base + lofs[t]; lcnt[t] = 0; }
    if (b == 0 && t == 0) off[N] = E;
    __syncthreads();
    for (int e = base + t; e < end; e += 256) {
        int2 en = stage[e];
        int d = en.y - lo;
        int p = atomicAdd(&lcnt[d], 1);
        csr[base + lofs[d] + p] = en.x;
    }
}

// =======================================================================
// GEMM-tiled MLP (round-4 structure, unchanged): per-lane weight loads,
// activations via LDS, nothing scalarized.
// =======================================================================
__global__ __launch_bounds__(256) void k_mlp(const float* __restrict__ h,
                                             const float* __restrict__ wa,  // [64][128] native
                                             const float* __restrict__ ba,  // [128]
                                             const float* __restrict__ wb,  // [128][64] native
                                             const float* __restrict__ bb,  // [64]
                                             float* __restrict__ m, int N)
{
    __shared__ float h_s[64 * 65];
    __shared__ float hid_s[H * 65];
    __shared__ float red_s[256];
    __shared__ float red_q[256];

    const int tid  = threadIdx.x;
    const int tidn = tid & 15;
    const int tidc = tid >> 4;
    const int wv   = tid >> 6;
    const int base = blockIdx.x * 64;

    {
        int sn = tid & 63;
        int sc = tid >> 6;
        int gn = min(base + sn, N - 1);
        const float4* hp = (const float4*)(h + (size_t)gn * D + sc * 16);
        float4 a = hp[0], b = hp[1], c = hp[2], d = hp[3];
        float* r = h_s + sn * 65 + sc * 16;
        r[0]=a.x;  r[1]=a.y;  r[2]=a.z;  r[3]=a.w;
        r[4]=b.x;  r[5]=b.y;  r[6]=b.z;  r[7]=b.w;
        r[8]=c.x;  r[9]=c.y;  r[10]=c.z; r[11]=c.w;
        r[12]=d.x; r[13]=d.y; r[14]=d.z; r[15]=d.w;
    }
    __syncthreads();

    float acc[4][8];
#pragma unroll
    for (int i = 0; i < 4; ++i)
#pragma unroll
        for (int c = 0; c < 8; ++c) acc[i][c] = 0.f;

#pragma unroll 4
    for (int k = 0; k < D; ++k) {
        float4 w0v = *(const float4*)(wa + k * H + tidc * 8);
        float4 w1v = *(const float4*)(wa + k * H + tidc * 8 + 4);
        float hv0 = h_s[tidn * 65 + k];
        float hv1 = h_s[(tidn + 16) * 65 + k];
        float hv2 = h_s[(tidn + 32) * 65 + k];
        float hv3 = h_s[(tidn + 48) * 65 + k];
#define P1(i, hv) \
        acc[i][0]=fmaf(hv,w0v.x,acc[i][0]); acc[i][1]=fmaf(hv,w0v.y,acc[i][1]); \
        acc[i][2]=fmaf(hv,w0v.z,acc[i][2]); acc[i][3]=fmaf(hv,w0v.w,acc[i][3]); \
        acc[i][4]=fmaf(hv,w1v.x,acc[i][4]); acc[i][5]=fmaf(hv,w1v.y,acc[i][5]); \
        acc[i][6]=fmaf(hv,w1v.z,acc[i][6]); acc[i][7]=fmaf(hv,w1v.w,acc[i][7]);
        P1(0, hv0) P1(1, hv1) P1(2, hv2) P1(3, hv3)
#undef P1
    }

    {
        float4 ba0 = *(const float4*)(ba + tidc * 8);
        float4 ba1 = *(const float4*)(ba + tidc * 8 + 4);
        float bav[8] = {ba0.x, ba0.y, ba0.z, ba0.w, ba1.x, ba1.y, ba1.z, ba1.w};
#pragma unroll
        for (int c = 0; c < 8; ++c) {
            float* row = hid_s + (tidc * 8 + c) * 65 + tidn;
#pragma unroll
            for (int i = 0; i < 4; ++i)
                row[16 * i] = fmaxf(acc[i][c] + bav[c], 0.f);
        }
    }
    __syncthreads();

    float o[4][4];
#pragma unroll
    for (int i = 0; i < 4; ++i)
#pragma unroll
        for (int j = 0; j < 4; ++j) o[i][j] = 0.f;

#pragma unroll 8
    for (int k = 0; k < H; ++k) {
        float4 wv4 = *(const float4*)(wb + k * D + tidc * 4);
        float d0 = hid_s[k * 65 + tidn];
        float d1 = hid_s[k * 65 + tidn + 16];
        float d2 = hid_s[k * 65 + tidn + 32];
        float d3 = hid_s[k * 65 + tidn + 48];
#define P2(i, dv) \
        o[i][0]=fmaf(dv,wv4.x,o[i][0]); o[i][1]=fmaf(dv,wv4.y,o[i][1]); \
        o[i][2]=fmaf(dv,wv4.z,o[i][2]); o[i][3]=fmaf(dv,wv4.w,o[i][3]);
        P2(0, d0) P2(1, d1) P2(2, d2) P2(3, d3)
#undef P2
    }

    float4 bbv = *(const float4*)(bb + tidc * 4);
    float bz[4] = {bbv.x, bbv.y, bbv.z, bbv.w};
    float s[4], q[4];
#pragma unroll
    for (int i = 0; i < 4; ++i) {
        float ss = 0.f, qq = 0.f;
#pragma unroll
        for (int j = 0; j < 4; ++j) {
            float t = o[i][j] + bz[j];
            t = t / (1.f + __expf(-t));
            o[i][j] = t;
            ss += t;
            qq = fmaf(t, t, qq);
        }
        s[i] = ss; q[i] = qq;
    }

#pragma unroll
    for (int i = 0; i < 4; ++i) {
        s[i] += __shfl_xor(s[i], 16, 64);
        s[i] += __shfl_xor(s[i], 32, 64);
        q[i] += __shfl_xor(q[i], 16, 64);
        q[i] += __shfl_xor(q[i], 32, 64);
    }
    if ((tidc & 3) == 0) {
#pragma unroll
        for (int i = 0; i < 4; ++i) {
            red_s[wv * 64 + i * 16 + tidn] = s[i];
            red_q[wv * 64 + i * 16 + tidn] = q[i];
        }
    }
    __syncthreads();

#pragma unroll
    for (int i = 0; i < 4; ++i) {
        int r = i * 16 + tidn;
        float ts = red_s[r] + red_s[64 + r] + red_s[128 + r] + red_s[192 + r];
        float tq = red_q[r] + red_q[64 + r] + red_q[128 + r] + red_q[192 + r];
        float mu  = ts * (1.f / D);
        float var = tq * (1.f / D) - mu * mu;
        float inv = rsqrtf(var + EPSL);
        int node = base + tidn + 16 * i;
        if (node < N) {
            float4 outv;
            outv.x = (o[i][0] - mu) * inv;
            outv.y = (o[i][1] - mu) * inv;
            outv.z = (o[i][2] - mu) * inv;
            outv.w = (o[i][3] - mu) * inv;
            *(float4*)(m + (size_t)node * D + tidc * 4) = outv;
        }
    }
}

__global__ __launch_bounds__(256) void k_init(const float* __restrict__ x,
                                              const float* __restrict__ w0,
                                              const float* __restrict__ b0,
                                              const float* __restrict__ w1,
                                              const float* __restrict__ b1,
                                              float* __restrict__ h, int N)
{
    __shared__ float x_s[64 * 17];
    __shared__ float hid_s[D * 65];
    __shared__ float red_s[256];
    __shared__ float red_q[256];

    const int tid  = threadIdx.x;
    const int tidn = tid & 15;
    const int tidc = tid >> 4;
    const int wv   = tid >> 6;
    const int base = blockIdx.x * 64;

    {
        int sn = tid & 63;
        int sc = tid >> 6;
        int gn = min(base + sn, N - 1);
        float4 xv = *(const float4*)(x + (size_t)gn * D_IN + sc * 4);
        float* r = x_s + sn * 17 + sc * 4;
        r[0] = xv.x; r[1] = xv.y; r[2] = xv.z; r[3] = xv.w;
    }
    __syncthreads();

    float a1[4][4];
#pragma unroll
    for (int i = 0; i < 4; ++i)
#pragma unroll
        for (int c = 0; c < 4; ++c) a1[i][c] = 0.f;

#pragma unroll
    for (int k = 0; k < D_IN; ++k) {
        float4 wv4 = *(const float4*)(w0 + k * D + tidc * 4);
        float x0 = x_s[tidn * 17 + k];
        float x1 = x_s[(tidn + 16) * 17 + k];
        float x2 = x_s[(tidn + 32) * 17 + k];
        float x3 = x_s[(tidn + 48) * 17 + k];
#define Q1(i, xv) \
        a1[i][0]=fmaf(xv,wv4.x,a1[i][0]); a1[i][1]=fmaf(xv,wv4.y,a1[i][1]); \
        a1[i][2]=fmaf(xv,wv4.z,a1[i][2]); a1[i][3]=fmaf(xv,wv4.w,a1[i][3]);
        Q1(0, x0) Q1(1, x1) Q1(2, x2) Q1(3, x3)
#undef Q1
    }

    {
        float4 b0v = *(const float4*)(b0 + tidc * 4);
        float bz0[4] = {b0v.x, b0v.y, b0v.z, b0v.w};
#pragma unroll
        for (int c = 0; c < 4; ++c) {
            float* row = hid_s + (tidc * 4 + c) * 65 + tidn;
#pragma unroll
            for (int i = 0; i < 4; ++i)
                row[16 * i] = fmaxf(a1[i][c] + bz0[c], 0.f);
        }
    }
    __syncthreads();

    float o[4][4];
#pragma unroll
    for (int i = 0; i < 4; ++i)
#pragma unroll
        for (int j = 0; j < 4; ++j) o[i][j] = 0.f;

#pragma unroll 8
    for (int k = 0; k < D; ++k) {
        float4 wv4 = *(const float4*)(w1 + k * D + tidc * 4);
        float d0 = hid_s[k * 65 + tidn];
        float d1 = hid_s[k * 65 + tidn + 16];
        float d2 = hid_s[k * 65 + tidn + 32];
        float d3 = hid_s[k * 65 + tidn + 48];
#define P2(i, dv) \
        o[i][0]=fmaf(dv,wv4.x,o[i][0]); o[i][1]=fmaf(dv,wv4.y,o[i][1]); \
        o[i][2]=fmaf(dv,wv4.z,o[i][2]); o[i][3]=fmaf(dv,wv4.w,o[i][3]);
        P2(0, d0) P2(1, d1) P2(2, d2) P2(3, d3)
#undef P2
    }

    float4 bbv = *(const float4*)(b1 + tidc * 4);
    float bz[4] = {bbv.x, bbv.y, bbv.z, bbv.w};
    float s[4], q[4];
#pragma unroll
    for (int i = 0; i < 4; ++i) {
        float ss = 0.f, qq = 0.f;
#pragma unroll
        for (int j = 0; j < 4; ++j) {
            float t = o[i][j] + bz[j];
            t = t / (1.f + __expf(-t));
            o[i][j] = t;
            ss += t;
            qq = fmaf(t, t, qq);
        }
        s[i] = ss; q[i] = qq;
    }
#pragma unroll
    for (int i = 0; i < 4; ++i) {
        s[i] += __shfl_xor(s[i], 16, 64);
        s[i] += __shfl_xor(s[i], 32, 64);
        q[i] += __shfl_xor(q[i], 16, 64);
        q[i] += __shfl_xor(q[i], 32, 64);
    }
    if ((tidc & 3) == 0) {
#pragma unroll
        for (int i = 0; i < 4; ++i) {
            red_s[wv * 64 + i * 16 + tidn] = s[i];
            red_q[wv * 64 + i * 16 + tidn] = q[i];
        }
    }
    __syncthreads();

#pragma unroll
    for (int i = 0; i < 4; ++i) {
        int r = i * 16 + tidn;
        float ts = red_s[r] + red_s[64 + r] + red_s[128 + r] + red_s[192 + r];
        float tq = red_q[r] + red_q[64 + r] + red_q[128 + r] + red_q[192 + r];
        float mu  = ts * (1.f / D);
        float var = tq * (1.f / D) - mu * mu;
        float inv = rsqrtf(var + EPSL);
        int node = base + tidn + 16 * i;
        if (node < N) {
            float4 outv;
            outv.x = (o[i][0] - mu) * inv;
            outv.y = (o[i][1] - mu) * inv;
            outv.z = (o[i][2] - mu) * inv;
            outv.w = (o[i][3] - mu) * inv;
            *(float4*)(h + (size_t)node * D + tidc * 4) = outv;
        }
    }
}

// ---------------- aggregation: h += segment_mean(m[src], dst) ------------------
// denominator = off[n+1]-off[n] (cnt array deleted with the old hist path)
__global__ __launch_bounds__(256) void k_agg(const float* __restrict__ m,
                                             const int* __restrict__ csr,
                                             const int* __restrict__ off,
                                             float* __restrict__ h, int N)
{
    int g = threadIdx.x >> 4;
    int c = threadIdx.x & 15;
    int node = blockIdx.x * 16 + g;
    if (node >= N) return;

    int b  = off[node];
    int e2 = off[node + 1];
    float4 s = {0.f, 0.f, 0.f, 0.f};
    for (int e = b; e < e2; ++e) {
        int sn = csr[e];
        float4 v = ((const float4*)(m + (size_t)sn * D))[c];
        s.x += v.x; s.y += v.y; s.z += v.z; s.w += v.w;
    }
    float dnm = fmaxf((float)(e2 - b), 1.f);
    float inv = 1.f / dnm;

    float4* hp = (float4*)(h + (size_t)node * D);
    float4 hv = hp[c];
    hv.x = fmaf(s.x, inv, hv.x);
    hv.y = fmaf(s.y, inv, hv.y);
    hv.z = fmaf(s.z, inv, hv.z);
    hv.w = fmaf(s.w, inv, hv.w);
    hp[c] = hv;
}

extern "C" void kernel_launch(void* const* d_in, const int* in_sizes, int n_in,
                              void* d_out, int out_size, void* d_ws, size_t ws_size,
                              hipStream_t stream)
{
    const float* x  = (const float*)d_in[0];
    const int*   ei = (const int*)d_in[1];
    const float* w0 = (const float*)d_in[2];
    const float* b0 = (const float*)d_in[3];
    const float* w1 = (const float*)d_in[4];
    const float* b1 = (const float*)d_in[5];
    const float* wa = (const float*)d_in[6];
    const float* ba = (const float*)d_in[7];
    const float* wb = (const float*)d_in[8];
    const float* bb = (const float*)d_in[9];

    const int N = in_sizes[0] / D_IN;
    const int E = in_sizes[1] / 2;
    const int L = in_sizes[6] / (D * H);
    const int B = (N + NPB - 1) >> NPB_SH;

    const int* src = ei;
    const int* dst = ei + E;

    // workspace layout (256B aligned chunks)
    char* ws = (char*)d_ws;
    size_t o = 0;
    auto carve = [&](size_t bytes) -> char* {
        char* p = ws + o;
        o = (o + bytes + 255) & ~(size_t)255;
        return p;
    };
    float* m     = (float*)carve((size_t)N * D * sizeof(float));
    int*   csr   = (int*)  carve((size_t)E * sizeof(int));
    int*   offp  = (int*)  carve((size_t)(N + 1) * sizeof(int));
    int2*  stage = (int2*) carve((size_t)E * sizeof(int2));
    int*   bc    = (int*)  carve((size_t)(2 * B) * sizeof(int));  // bcnt | btail
    int*   bbase = (int*)  carve((size_t)B * sizeof(int));

    int* bcnt  = bc;
    int* btail = bc + B;

    float* h = (float*)d_out;

    const int nb = (N + 63) / 64;
    const int ge = (E + 255) / 256;

    k_zero<<<(2 * B + 255) / 256, 256, 0, stream>>>(bc, 2 * B);
    k_bhist<<<ge, 256, 0, stream>>>(dst, bcnt, E);
    k_bscan<<<1, 1024, 0, stream>>>(bcnt, bbase, B);
    k_stage<<<ge, 256, 0, stream>>>(src, dst, bbase, btail, stage, E);
    k_build<<<B, 256, 0, stream>>>(stage, bbase, offp, csr, N, E, B);

    k_init<<<nb, 256, 0, stream>>>(x, w0, b0, w1, b1, h, N);

    for (int l = 0; l < L; ++l) {
        k_mlp<<<nb, 256, 0, stream>>>(h, wa + (size_t)l * D * H,
                                      ba + (size_t)l * H,
                                      wb + (size_t)l * H * D,
                                      bb + (size_t)l * D, m, N);
        k_agg<<<(N + 15) / 16, 256, 0, stream>>>(m, csr, offp, h, N);
    }
}

// Round 6
// 402.863 us; speedup vs baseline: 1.8258x; 1.8258x over previous
//
#include <hip/hip_runtime.h>
#include <math.h>

#define D_IN 16
#define D    64
#define H    128
#define EPSL 1e-5f

// =======================================================================
// CSR build, round-4 structure (hist + hierarchical scan) with one change:
// k_fill_x groups csr writes by XCD. Round-4's k_fill had 17x write amp
// (55.7MB for 3.2MB of csr): each 64B csr line receives ~16 stores from
// blocks spread over 8 non-coherent XCD L2s -> one partial-line writeback
// per store burst. k_fill_x: block group g = bid&7 processes only edges
// with (dst>>4)&7 == g (blocks within a group grid-stride disjoint edge
// ranges -> each edge handled exactly once, independent of dispatch).
// With the round-robin bid->XCD mapping, all stores to a csr line come
// from ONE XCD: the line stays in that L2 and evicts once.
// Round-5's staged variant is reverted: 782-counter atomic tails serialized
// at the coherence point (190us) and the int2 scatter paid write-amp anyway.
// =======================================================================

__global__ void k_zero(int* __restrict__ p, int n)
{
    int i = blockIdx.x * blockDim.x + threadIdx.x;
    if (i < n) p[i] = 0;
}

__global__ void k_hist(const int* __restrict__ dst, int* __restrict__ cnt, int E)
{
    int i = blockIdx.x * blockDim.x + threadIdx.x;
    if (i < E) atomicAdd(&cnt[dst[i]], 1);
}

__global__ void k_scan_blk(const int* __restrict__ cnt, int* __restrict__ off,
                           int* __restrict__ bsum, int N)
{
    __shared__ int sm[256];
    int t = threadIdx.x;
    int g = blockIdx.x * 256 + t;
    int v = (g < N) ? cnt[g] : 0;
    sm[t] = v;
    __syncthreads();
    for (int d2 = 1; d2 < 256; d2 <<= 1) {
        int u = (t >= d2) ? sm[t - d2] : 0;
        __syncthreads();
        sm[t] += u;
        __syncthreads();
    }
    if (g < N) off[g + 1] = sm[t];
    if (t == 255) bsum[blockIdx.x] = sm[255];
}

__global__ void k_scan_top(int* __restrict__ bsum, int G)
{
    __shared__ int sm[1024];
    int t = threadIdx.x;
    int v = (t < G) ? bsum[t] : 0;
    sm[t] = v;
    __syncthreads();
    for (int d2 = 1; d2 < 1024; d2 <<= 1) {
        int u = (t >= d2) ? sm[t - d2] : 0;
        __syncthreads();
        sm[t] += u;
        __syncthreads();
    }
    if (t < G) bsum[t] = sm[t] - v;   // exclusive
}

__global__ void k_scan_add(int* __restrict__ off, const int* __restrict__ bsum, int N)
{
    int g = blockIdx.x * 256 + threadIdx.x;
    if (g < N) off[g + 1] += bsum[blockIdx.x];
    if (g == 0) off[0] = 0;
}

// XCD-grouped CSR fill (see header comment). Grid must be a multiple of 8.
__global__ __launch_bounds__(256) void k_fill_x(const int* __restrict__ src,
                                                const int* __restrict__ dst,
                                                const int* __restrict__ off,
                                                int* __restrict__ fill,
                                                int* __restrict__ csr, int E)
{
    int g = blockIdx.x & 7;          // write-locality group (~XCD)
    int j = blockIdx.x >> 3;         // block index within group
    int J = gridDim.x >> 3;          // blocks per group
    for (int e = j * 256 + threadIdx.x; e < E; e += J * 256) {
        int d = dst[e];
        if (((d >> 4) & 7) == g) {
            int p = atomicAdd(&fill[d], 1);
            csr[off[d] + p] = src[e];
        }
    }
}

// =======================================================================
// GEMM-tiled MLP (round-4 structure, unchanged): per-lane weight loads,
// activations via LDS, nothing scalarized.
// =======================================================================
__global__ __launch_bounds__(256) void k_mlp(const float* __restrict__ h,
                                             const float* __restrict__ wa,  // [64][128] native
                                             const float* __restrict__ ba,  // [128]
                                             const float* __restrict__ wb,  // [128][64] native
                                             const float* __restrict__ bb,  // [64]
                                             float* __restrict__ m, int N)
{
    __shared__ float h_s[64 * 65];
    __shared__ float hid_s[H * 65];
    __shared__ float red_s[256];
    __shared__ float red_q[256];

    const int tid  = threadIdx.x;
    const int tidn = tid & 15;
    const int tidc = tid >> 4;
    const int wv   = tid >> 6;
    const int base = blockIdx.x * 64;

    {
        int sn = tid & 63;
        int sc = tid >> 6;
        int gn = min(base + sn, N - 1);
        const float4* hp = (const float4*)(h + (size_t)gn * D + sc * 16);
        float4 a = hp[0], b = hp[1], c = hp[2], d = hp[3];
        float* r = h_s + sn * 65 + sc * 16;
        r[0]=a.x;  r[1]=a.y;  r[2]=a.z;  r[3]=a.w;
        r[4]=b.x;  r[5]=b.y;  r[6]=b.z;  r[7]=b.w;
        r[8]=c.x;  r[9]=c.y;  r[10]=c.z; r[11]=c.w;
        r[12]=d.x; r[13]=d.y; r[14]=d.z; r[15]=d.w;
    }
    __syncthreads();

    float acc[4][8];
#pragma unroll
    for (int i = 0; i < 4; ++i)
#pragma unroll
        for (int c = 0; c < 8; ++c) acc[i][c] = 0.f;

#pragma unroll 4
    for (int k = 0; k < D; ++k) {
        float4 w0v = *(const float4*)(wa + k * H + tidc * 8);
        float4 w1v = *(const float4*)(wa + k * H + tidc * 8 + 4);
        float hv0 = h_s[tidn * 65 + k];
        float hv1 = h_s[(tidn + 16) * 65 + k];
        float hv2 = h_s[(tidn + 32) * 65 + k];
        float hv3 = h_s[(tidn + 48) * 65 + k];
#define P1(i, hv) \
        acc[i][0]=fmaf(hv,w0v.x,acc[i][0]); acc[i][1]=fmaf(hv,w0v.y,acc[i][1]); \
        acc[i][2]=fmaf(hv,w0v.z,acc[i][2]); acc[i][3]=fmaf(hv,w0v.w,acc[i][3]); \
        acc[i][4]=fmaf(hv,w1v.x,acc[i][4]); acc[i][5]=fmaf(hv,w1v.y,acc[i][5]); \
        acc[i][6]=fmaf(hv,w1v.z,acc[i][6]); acc[i][7]=fmaf(hv,w1v.w,acc[i][7]);
        P1(0, hv0) P1(1, hv1) P1(2, hv2) P1(3, hv3)
#undef P1
    }

    {
        float4 ba0 = *(const float4*)(ba + tidc * 8);
        float4 ba1 = *(const float4*)(ba + tidc * 8 + 4);
        float bav[8] = {ba0.x, ba0.y, ba0.z, ba0.w, ba1.x, ba1.y, ba1.z, ba1.w};
#pragma unroll
        for (int c = 0; c < 8; ++c) {
            float* row = hid_s + (tidc * 8 + c) * 65 + tidn;
#pragma unroll
            for (int i = 0; i < 4; ++i)
                row[16 * i] = fmaxf(acc[i][c] + bav[c], 0.f);
        }
    }
    __syncthreads();

    float o[4][4];
#pragma unroll
    for (int i = 0; i < 4; ++i)
#pragma unroll
        for (int j = 0; j < 4; ++j) o[i][j] = 0.f;

#pragma unroll 8
    for (int k = 0; k < H; ++k) {
        float4 wv4 = *(const float4*)(wb + k * D + tidc * 4);
        float d0 = hid_s[k * 65 + tidn];
        float d1 = hid_s[k * 65 + tidn + 16];
        float d2 = hid_s[k * 65 + tidn + 32];
        float d3 = hid_s[k * 65 + tidn + 48];
#define P2(i, dv) \
        o[i][0]=fmaf(dv,wv4.x,o[i][0]); o[i][1]=fmaf(dv,wv4.y,o[i][1]); \
        o[i][2]=fmaf(dv,wv4.z,o[i][2]); o[i][3]=fmaf(dv,wv4.w,o[i][3]);
        P2(0, d0) P2(1, d1) P2(2, d2) P2(3, d3)
#undef P2
    }

    float4 bbv = *(const float4*)(bb + tidc * 4);
    float bz[4] = {bbv.x, bbv.y, bbv.z, bbv.w};
    float s[4], q[4];
#pragma unroll
    for (int i = 0; i < 4; ++i) {
        float ss = 0.f, qq = 0.f;
#pragma unroll
        for (int j = 0; j < 4; ++j) {
            float t = o[i][j] + bz[j];
            t = t / (1.f + __expf(-t));
            o[i][j] = t;
            ss += t;
            qq = fmaf(t, t, qq);
        }
        s[i] = ss; q[i] = qq;
    }

#pragma unroll
    for (int i = 0; i < 4; ++i) {
        s[i] += __shfl_xor(s[i], 16, 64);
        s[i] += __shfl_xor(s[i], 32, 64);
        q[i] += __shfl_xor(q[i], 16, 64);
        q[i] += __shfl_xor(q[i], 32, 64);
    }
    if ((tidc & 3) == 0) {
#pragma unroll
        for (int i = 0; i < 4; ++i) {
            red_s[wv * 64 + i * 16 + tidn] = s[i];
            red_q[wv * 64 + i * 16 + tidn] = q[i];
        }
    }
    __syncthreads();

#pragma unroll
    for (int i = 0; i < 4; ++i) {
        int r = i * 16 + tidn;
        float ts = red_s[r] + red_s[64 + r] + red_s[128 + r] + red_s[192 + r];
        float tq = red_q[r] + red_q[64 + r] + red_q[128 + r] + red_q[192 + r];
        float mu  = ts * (1.f / D);
        float var = tq * (1.f / D) - mu * mu;
        float inv = rsqrtf(var + EPSL);
        int node = base + tidn + 16 * i;
        if (node < N) {
            float4 outv;
            outv.x = (o[i][0] - mu) * inv;
            outv.y = (o[i][1] - mu) * inv;
            outv.z = (o[i][2] - mu) * inv;
            outv.w = (o[i][3] - mu) * inv;
            *(float4*)(m + (size_t)node * D + tidc * 4) = outv;
        }
    }
}

__global__ __launch_bounds__(256) void k_init(const float* __restrict__ x,
                                              const float* __restrict__ w0,
                                              const float* __restrict__ b0,
                                              const float* __restrict__ w1,
                                              const float* __restrict__ b1,
                                              float* __restrict__ h, int N)
{
    __shared__ float x_s[64 * 17];
    __shared__ float hid_s[D * 65];
    __shared__ float red_s[256];
    __shared__ float red_q[256];

    const int tid  = threadIdx.x;
    const int tidn = tid & 15;
    const int tidc = tid >> 4;
    const int wv   = tid >> 6;
    const int base = blockIdx.x * 64;

    {
        int sn = tid & 63;
        int sc = tid >> 6;
        int gn = min(base + sn, N - 1);
        float4 xv = *(const float4*)(x + (size_t)gn * D_IN + sc * 4);
        float* r = x_s + sn * 17 + sc * 4;
        r[0] = xv.x; r[1] = xv.y; r[2] = xv.z; r[3] = xv.w;
    }
    __syncthreads();

    float a1[4][4];
#pragma unroll
    for (int i = 0; i < 4; ++i)
#pragma unroll
        for (int c = 0; c < 4; ++c) a1[i][c] = 0.f;

#pragma unroll
    for (int k = 0; k < D_IN; ++k) {
        float4 wv4 = *(const float4*)(w0 + k * D + tidc * 4);
        float x0 = x_s[tidn * 17 + k];
        float x1 = x_s[(tidn + 16) * 17 + k];
        float x2 = x_s[(tidn + 32) * 17 + k];
        float x3 = x_s[(tidn + 48) * 17 + k];
#define Q1(i, xv) \
        a1[i][0]=fmaf(xv,wv4.x,a1[i][0]); a1[i][1]=fmaf(xv,wv4.y,a1[i][1]); \
        a1[i][2]=fmaf(xv,wv4.z,a1[i][2]); a1[i][3]=fmaf(xv,wv4.w,a1[i][3]);
        Q1(0, x0) Q1(1, x1) Q1(2, x2) Q1(3, x3)
#undef Q1
    }

    {
        float4 b0v = *(const float4*)(b0 + tidc * 4);
        float bz0[4] = {b0v.x, b0v.y, b0v.z, b0v.w};
#pragma unroll
        for (int c = 0; c < 4; ++c) {
            float* row = hid_s + (tidc * 4 + c) * 65 + tidn;
#pragma unroll
            for (int i = 0; i < 4; ++i)
                row[16 * i] = fmaxf(a1[i][c] + bz0[c], 0.f);
        }
    }
    __syncthreads();

    float o[4][4];
#pragma unroll
    for (int i = 0; i < 4; ++i)
#pragma unroll
        for (int j = 0; j < 4; ++j) o[i][j] = 0.f;

#pragma unroll 8
    for (int k = 0; k < D; ++k) {
        float4 wv4 = *(const float4*)(w1 + k * D + tidc * 4);
        float d0 = hid_s[k * 65 + tidn];
        float d1 = hid_s[k * 65 + tidn + 16];
        float d2 = hid_s[k * 65 + tidn + 32];
        float d3 = hid_s[k * 65 + tidn + 48];
#define P2(i, dv) \
        o[i][0]=fmaf(dv,wv4.x,o[i][0]); o[i][1]=fmaf(dv,wv4.y,o[i][1]); \
        o[i][2]=fmaf(dv,wv4.z,o[i][2]); o[i][3]=fmaf(dv,wv4.w,o[i][3]);
        P2(0, d0) P2(1, d1) P2(2, d2) P2(3, d3)
#undef P2
    }

    float4 bbv = *(const float4*)(b1 + tidc * 4);
    float bz[4] = {bbv.x, bbv.y, bbv.z, bbv.w};
    float s[4], q[4];
#pragma unroll
    for (int i = 0; i < 4; ++i) {
        float ss = 0.f, qq = 0.f;
#pragma unroll
        for (int j = 0; j < 4; ++j) {
            float t = o[i][j] + bz[j];
            t = t / (1.f + __expf(-t));
            o[i][j] = t;
            ss += t;
            qq = fmaf(t, t, qq);
        }
        s[i] = ss; q[i] = qq;
    }
#pragma unroll
    for (int i = 0; i < 4; ++i) {
        s[i] += __shfl_xor(s[i], 16, 64);
        s[i] += __shfl_xor(s[i], 32, 64);
        q[i] += __shfl_xor(q[i], 16, 64);
        q[i] += __shfl_xor(q[i], 32, 64);
    }
    if ((tidc & 3) == 0) {
#pragma unroll
        for (int i = 0; i < 4; ++i) {
            red_s[wv * 64 + i * 16 + tidn] = s[i];
            red_q[wv * 64 + i * 16 + tidn] = q[i];
        }
    }
    __syncthreads();

#pragma unroll
    for (int i = 0; i < 4; ++i) {
        int r = i * 16 + tidn;
        float ts = red_s[r] + red_s[64 + r] + red_s[128 + r] + red_s[192 + r];
        float tq = red_q[r] + red_q[64 + r] + red_q[128 + r] + red_q[192 + r];
        float mu  = ts * (1.f / D);
        float var = tq * (1.f / D) - mu * mu;
        float inv = rsqrtf(var + EPSL);
        int node = base + tidn + 16 * i;
        if (node < N) {
            float4 outv;
            outv.x = (o[i][0] - mu) * inv;
            outv.y = (o[i][1] - mu) * inv;
            outv.z = (o[i][2] - mu) * inv;
            outv.w = (o[i][3] - mu) * inv;
            *(float4*)(h + (size_t)node * D + tidc * 4) = outv;
        }
    }
}

// ---------------- aggregation: h += segment_mean(m[src], dst) ------------------
// unroll-by-2 with dual accumulators: 2 gather lines in flight per wave iter
__global__ __launch_bounds__(256) void k_agg(const float* __restrict__ m,
                                             const int* __restrict__ csr,
                                             const int* __restrict__ off,
                                             float* __restrict__ h, int N)
{
    int g = threadIdx.x >> 4;
    int c = threadIdx.x & 15;
    int node = blockIdx.x * 16 + g;
    if (node >= N) return;

    int b  = off[node];
    int e2 = off[node + 1];
    float4 s0 = {0.f, 0.f, 0.f, 0.f};
    float4 s1 = {0.f, 0.f, 0.f, 0.f};
    int e = b;
    for (; e + 2 <= e2; e += 2) {
        int sn0 = csr[e];
        int sn1 = csr[e + 1];
        float4 v0 = ((const float4*)(m + (size_t)sn0 * D))[c];
        float4 v1 = ((const float4*)(m + (size_t)sn1 * D))[c];
        s0.x += v0.x; s0.y += v0.y; s0.z += v0.z; s0.w += v0.w;
        s1.x += v1.x; s1.y += v1.y; s1.z += v1.z; s1.w += v1.w;
    }
    if (e < e2) {
        int sn = csr[e];
        float4 v = ((const float4*)(m + (size_t)sn * D))[c];
        s0.x += v.x; s0.y += v.y; s0.z += v.z; s0.w += v.w;
    }
    s0.x += s1.x; s0.y += s1.y; s0.z += s1.z; s0.w += s1.w;

    float dnm = fmaxf((float)(e2 - b), 1.f);
    float inv = 1.f / dnm;

    float4* hp = (float4*)(h + (size_t)node * D);
    float4 hv = hp[c];
    hv.x = fmaf(s0.x, inv, hv.x);
    hv.y = fmaf(s0.y, inv, hv.y);
    hv.z = fmaf(s0.z, inv, hv.z);
    hv.w = fmaf(s0.w, inv, hv.w);
    hp[c] = hv;
}

extern "C" void kernel_launch(void* const* d_in, const int* in_sizes, int n_in,
                              void* d_out, int out_size, void* d_ws, size_t ws_size,
                              hipStream_t stream)
{
    const float* x  = (const float*)d_in[0];
    const int*   ei = (const int*)d_in[1];
    const float* w0 = (const float*)d_in[2];
    const float* b0 = (const float*)d_in[3];
    const float* w1 = (const float*)d_in[4];
    const float* b1 = (const float*)d_in[5];
    const float* wa = (const float*)d_in[6];
    const float* ba = (const float*)d_in[7];
    const float* wb = (const float*)d_in[8];
    const float* bb = (const float*)d_in[9];

    const int N = in_sizes[0] / D_IN;
    const int E = in_sizes[1] / 2;
    const int L = in_sizes[6] / (D * H);

    const int* src = ei;
    const int* dst = ei + E;

    // workspace layout (256B aligned chunks)
    char* ws = (char*)d_ws;
    size_t o = 0;
    auto carve = [&](size_t bytes) -> char* {
        char* p = ws + o;
        o = (o + bytes + 255) & ~(size_t)255;
        return p;
    };
    float* m    = (float*)carve((size_t)N * D * sizeof(float));
    int*   csr  = (int*)  carve((size_t)E * sizeof(int));
    int*   cnt  = (int*)  carve((size_t)N * sizeof(int));
    int*   fill = (int*)  carve((size_t)N * sizeof(int));
    int*   offp = (int*)  carve((size_t)(N + 1) * sizeof(int));
    int*   bsum = (int*)  carve((size_t)1024 * sizeof(int));

    float* h = (float*)d_out;

    const int nb = (N + 63) / 64;
    const int G1 = (N + 255) / 256;

    k_zero<<<(N + 255) / 256, 256, 0, stream>>>(cnt, N);
    k_zero<<<(N + 255) / 256, 256, 0, stream>>>(fill, N);
    k_hist<<<(E + 255) / 256, 256, 0, stream>>>(dst, cnt, E);
    k_scan_blk<<<G1, 256, 0, stream>>>(cnt, offp, bsum, N);
    k_scan_top<<<1, 1024, 0, stream>>>(bsum, G1);
    k_scan_add<<<G1, 256, 0, stream>>>(offp, bsum, N);
    k_fill_x<<<2048, 256, 0, stream>>>(src, dst, offp, fill, csr, E);

    k_init<<<nb, 256, 0, stream>>>(x, w0, b0, w1, b1, h, N);

    for (int l = 0; l < L; ++l) {
        k_mlp<<<nb, 256, 0, stream>>>(h, wa + (size_t)l * D * H,
                                      ba + (size_t)l * H,
                                      wb + (size_t)l * H * D,
                                      bb + (size_t)l * D, m, N);
        k_agg<<<(N + 15) / 16, 256, 0, stream>>>(m, csr, offp, h, N);
    }
}

// Round 7
// 395.441 us; speedup vs baseline: 1.8600x; 1.0188x over previous
//
#include <hip/hip_runtime.h>
#include <math.h>

#define D_IN 16
#define D    64
#define H    128
#define EPSL 1e-5f

// =======================================================================
// Preprocessing (round-6 proven): hist + hierarchical scan + XCD-grouped
// fill (k_fill_x: block group g=bid&7 handles edges with (dst>>4)&7==g so
// all stores to a csr line come from one XCD's L2 -> one writeback/line).
// =======================================================================

__global__ void k_zero(int* __restrict__ p, int n)
{
    int i = blockIdx.x * blockDim.x + threadIdx.x;
    if (i < n) p[i] = 0;
}

__global__ void k_hist(const int* __restrict__ dst, int* __restrict__ cnt, int E)
{
    int i = blockIdx.x * blockDim.x + threadIdx.x;
    if (i < E) atomicAdd(&cnt[dst[i]], 1);
}

__global__ void k_scan_blk(const int* __restrict__ cnt, int* __restrict__ off,
                           int* __restrict__ bsum, int N)
{
    __shared__ int sm[256];
    int t = threadIdx.x;
    int g = blockIdx.x * 256 + t;
    int v = (g < N) ? cnt[g] : 0;
    sm[t] = v;
    __syncthreads();
    for (int d2 = 1; d2 < 256; d2 <<= 1) {
        int u = (t >= d2) ? sm[t - d2] : 0;
        __syncthreads();
        sm[t] += u;
        __syncthreads();
    }
    if (g < N) off[g + 1] = sm[t];
    if (t == 255) bsum[blockIdx.x] = sm[255];
}

__global__ void k_scan_top(int* __restrict__ bsum, int G)
{
    __shared__ int sm[1024];
    int t = threadIdx.x;
    int v = (t < G) ? bsum[t] : 0;
    sm[t] = v;
    __syncthreads();
    for (int d2 = 1; d2 < 1024; d2 <<= 1) {
        int u = (t >= d2) ? sm[t - d2] : 0;
        __syncthreads();
        sm[t] += u;
        __syncthreads();
    }
    if (t < G) bsum[t] = sm[t] - v;   // exclusive
}

__global__ void k_scan_add(int* __restrict__ off, const int* __restrict__ bsum, int N)
{
    int g = blockIdx.x * 256 + threadIdx.x;
    if (g < N) off[g + 1] += bsum[blockIdx.x];
    if (g == 0) off[0] = 0;
}

__global__ __launch_bounds__(256) void k_fill_x(const int* __restrict__ src,
                                                const int* __restrict__ dst,
                                                const int* __restrict__ off,
                                                int* __restrict__ fill,
                                                int* __restrict__ csr, int E)
{
    int g = blockIdx.x & 7;
    int j = blockIdx.x >> 3;
    int J = gridDim.x >> 3;
    for (int e = j * 256 + threadIdx.x; e < E; e += J * 256) {
        int d = dst[e];
        if (((d >> 4) & 7) == g) {
            int p = atomicAdd(&fill[d], 1);
            csr[off[d] + p] = src[e];
        }
    }
}

// =======================================================================
// GEMM-tiled MLP v2: feature-major LDS layouts so EVERY inner-loop LDS
// access is one ds_read_b128 (round 6: 768 ds_read_b32/thread put ~25us
// on the shared LDS pipe). Mapping: ch=tid&15 (channel group), q=tid>>4
// (node quad: nodes 4q..4q+3). hT[k][node]; gT[j2][node] with 16B-chunk
// swizzle chunk = q ^ (row>>3) -> per-quarter-wave writes hit 16 distinct
// bank-quads; readers use the same XOR with k>>3. LN reduces over the 16
// in-wave channel owners via shfl_xor (red buffers + 1 barrier deleted).
// =======================================================================
__global__ __launch_bounds__(256) void k_mlp(const float* __restrict__ h,
                                             const float* __restrict__ wa,  // [64][128]
                                             const float* __restrict__ ba,  // [128]
                                             const float* __restrict__ wb,  // [128][64]
                                             const float* __restrict__ bb,  // [64]
                                             float* __restrict__ m, int N)
{
    __shared__ __align__(16) float hT[D * 64];   // [k][node] 16KB
    __shared__ __align__(16) float gT[H * 64];   // [j2][node] swizzled 32KB

    const int tid  = threadIdx.x;
    const int ch   = tid & 15;
    const int q    = tid >> 4;          // node quad 0..15
    const int base = blockIdx.x * 64;

    // stage h -> hT (transposed). b32 writes, lanes consecutive: 2-way, free.
    {
        int sn = tid & 63;
        int sc = tid >> 6;
        int gn = min(base + sn, N - 1);
        const float4* hp = (const float4*)(h + (size_t)gn * D + sc * 16);
        float4 a = hp[0], b = hp[1], c4 = hp[2], d4 = hp[3];
        float* w = hT + (sc * 16) * 64 + sn;
        w[0*64]=a.x;  w[1*64]=a.y;  w[2*64]=a.z;  w[3*64]=a.w;
        w[4*64]=b.x;  w[5*64]=b.y;  w[6*64]=b.z;  w[7*64]=b.w;
        w[8*64]=c4.x; w[9*64]=c4.y; w[10*64]=c4.z; w[11*64]=c4.w;
        w[12*64]=d4.x; w[13*64]=d4.y; w[14*64]=d4.z; w[15*64]=d4.w;
    }
    __syncthreads();

    // phase 1: acc[node i][hid ch c] for hidden channels 8ch..8ch+7
    float acc[4][8];
#pragma unroll
    for (int i = 0; i < 4; ++i)
#pragma unroll
        for (int c = 0; c < 8; ++c) acc[i][c] = 0.f;

#pragma unroll 4
    for (int k = 0; k < D; ++k) {
        float4 wA = *(const float4*)(wa + k * H + ch * 8);
        float4 wB = *(const float4*)(wa + k * H + ch * 8 + 4);
        float4 hv = *(const float4*)(hT + k * 64 + q * 4);   // 1 b128, broadcast
#define PP(i, hc) \
        acc[i][0]=fmaf(hc,wA.x,acc[i][0]); acc[i][1]=fmaf(hc,wA.y,acc[i][1]); \
        acc[i][2]=fmaf(hc,wA.z,acc[i][2]); acc[i][3]=fmaf(hc,wA.w,acc[i][3]); \
        acc[i][4]=fmaf(hc,wB.x,acc[i][4]); acc[i][5]=fmaf(hc,wB.y,acc[i][5]); \
        acc[i][6]=fmaf(hc,wB.z,acc[i][6]); acc[i][7]=fmaf(hc,wB.w,acc[i][7]);
        PP(0, hv.x) PP(1, hv.y) PP(2, hv.z) PP(3, hv.w)
#undef PP
    }

    // relu + write hid: rows r=8ch+c, chunk-swizzled b128 (conflict-free)
    {
        float4 b0v = *(const float4*)(ba + ch * 8);
        float4 b1v = *(const float4*)(ba + ch * 8 + 4);
        float bav[8] = {b0v.x, b0v.y, b0v.z, b0v.w, b1v.x, b1v.y, b1v.z, b1v.w};
        int chunk = q ^ ch;             // = q ^ (r>>3), r = 8ch+c
#pragma unroll
        for (int c = 0; c < 8; ++c) {
            int r = ch * 8 + c;
            float4 t;
            t.x = fmaxf(acc[0][c] + bav[c], 0.f);
            t.y = fmaxf(acc[1][c] + bav[c], 0.f);
            t.z = fmaxf(acc[2][c] + bav[c], 0.f);
            t.w = fmaxf(acc[3][c] + bav[c], 0.f);
            *(float4*)(gT + r * 64 + chunk * 4) = t;
        }
    }
    __syncthreads();

    // phase 2: o[node i] over out channels 4ch..4ch+3
    float4 o0 = {0,0,0,0}, o1 = {0,0,0,0}, o2 = {0,0,0,0}, o3 = {0,0,0,0};
#pragma unroll 8
    for (int k = 0; k < H; ++k) {
        float4 w = *(const float4*)(wb + k * D + ch * 4);
        int chunk = q ^ ((k >> 3) & 15);
        float4 g = *(const float4*)(gT + k * 64 + chunk * 4);  // 1 b128
        o0.x=fmaf(g.x,w.x,o0.x); o0.y=fmaf(g.x,w.y,o0.y); o0.z=fmaf(g.x,w.z,o0.z); o0.w=fmaf(g.x,w.w,o0.w);
        o1.x=fmaf(g.y,w.x,o1.x); o1.y=fmaf(g.y,w.y,o1.y); o1.z=fmaf(g.y,w.z,o1.z); o1.w=fmaf(g.y,w.w,o1.w);
        o2.x=fmaf(g.z,w.x,o2.x); o2.y=fmaf(g.z,w.y,o2.y); o2.z=fmaf(g.z,w.z,o2.z); o2.w=fmaf(g.z,w.w,o2.w);
        o3.x=fmaf(g.w,w.x,o3.x); o3.y=fmaf(g.w,w.y,o3.y); o3.z=fmaf(g.w,w.z,o3.z); o3.w=fmaf(g.w,w.w,o3.w);
    }

    // bias + SiLU + LN (reduce across the 16 in-wave channel owners)
    float4 bbv = *(const float4*)(bb + ch * 4);
    float s[4], qv[4];
#define FIN(i, ov) { \
        ov.x += bbv.x; ov.y += bbv.y; ov.z += bbv.z; ov.w += bbv.w; \
        ov.x = ov.x / (1.f + __expf(-ov.x)); ov.y = ov.y / (1.f + __expf(-ov.y)); \
        ov.z = ov.z / (1.f + __expf(-ov.z)); ov.w = ov.w / (1.f + __expf(-ov.w)); \
        s[i]  = (ov.x + ov.y) + (ov.z + ov.w); \
        qv[i] = fmaf(ov.x, ov.x, fmaf(ov.y, ov.y, fmaf(ov.z, ov.z, ov.w * ov.w))); }
    FIN(0, o0) FIN(1, o1) FIN(2, o2) FIN(3, o3)
#undef FIN

#pragma unroll
    for (int d2 = 1; d2 < 16; d2 <<= 1) {
#pragma unroll
        for (int i = 0; i < 4; ++i) {
            s[i]  += __shfl_xor(s[i],  d2, 64);
            qv[i] += __shfl_xor(qv[i], d2, 64);
        }
    }

#pragma unroll
    for (int i = 0; i < 4; ++i) {
        float mu  = s[i] * (1.f / D);
        float var = qv[i] * (1.f / D) - mu * mu;
        float inv = rsqrtf(var + EPSL);
        int node = base + q * 4 + i;
        if (node < N) {
            float4 ov = (i == 0) ? o0 : (i == 1) ? o1 : (i == 2) ? o2 : o3;
            float4 outv;
            outv.x = (ov.x - mu) * inv;
            outv.y = (ov.y - mu) * inv;
            outv.z = (ov.z - mu) * inv;
            outv.w = (ov.w - mu) * inv;
            *(float4*)(m + (size_t)node * D + ch * 4) = outv;
        }
    }
}

// =======================================================================
// Initial embedding, same v2 structure (k=16 then k=64).
// =======================================================================
__global__ __launch_bounds__(256) void k_init(const float* __restrict__ x,
                                              const float* __restrict__ w0,  // [16][64]
                                              const float* __restrict__ b0,
                                              const float* __restrict__ w1,  // [64][64]
                                              const float* __restrict__ b1,
                                              float* __restrict__ h, int N)
{
    __shared__ __align__(16) float xT[D_IN * 64];  // [k][node] 4KB
    __shared__ __align__(16) float gT[D * 64];     // [hid][node] swizzled 16KB

    const int tid  = threadIdx.x;
    const int ch   = tid & 15;
    const int q    = tid >> 4;
    const int base = blockIdx.x * 64;

    {
        int sn = tid & 63;
        int sc = tid >> 6;
        int gn = min(base + sn, N - 1);
        float4 xv = *(const float4*)(x + (size_t)gn * D_IN + sc * 4);
        float* w = xT + (sc * 4) * 64 + sn;
        w[0*64] = xv.x; w[1*64] = xv.y; w[2*64] = xv.z; w[3*64] = xv.w;
    }
    __syncthreads();

    // phase 1: hidden channels 4ch..4ch+3
    float acc[4][4];
#pragma unroll
    for (int i = 0; i < 4; ++i)
#pragma unroll
        for (int c = 0; c < 4; ++c) acc[i][c] = 0.f;

#pragma unroll
    for (int k = 0; k < D_IN; ++k) {
        float4 w = *(const float4*)(w0 + k * D + ch * 4);
        float4 xv = *(const float4*)(xT + k * 64 + q * 4);
#define PP(i, xc) \
        acc[i][0]=fmaf(xc,w.x,acc[i][0]); acc[i][1]=fmaf(xc,w.y,acc[i][1]); \
        acc[i][2]=fmaf(xc,w.z,acc[i][2]); acc[i][3]=fmaf(xc,w.w,acc[i][3]);
        PP(0, xv.x) PP(1, xv.y) PP(2, xv.z) PP(3, xv.w)
#undef PP
    }

    {
        float4 b0v = *(const float4*)(b0 + ch * 4);
        float bav[4] = {b0v.x, b0v.y, b0v.z, b0v.w};
        int chunk = q ^ (ch >> 1);      // = q ^ (r>>3), r = 4ch+c
#pragma unroll
        for (int c = 0; c < 4; ++c) {
            int r = ch * 4 + c;
            float4 t;
            t.x = fmaxf(acc[0][c] + bav[c], 0.f);
            t.y = fmaxf(acc[1][c] + bav[c], 0.f);
            t.z = fmaxf(acc[2][c] + bav[c], 0.f);
            t.w = fmaxf(acc[3][c] + bav[c], 0.f);
            *(float4*)(gT + r * 64 + chunk * 4) = t;
        }
    }
    __syncthreads();

    float4 o0 = {0,0,0,0}, o1 = {0,0,0,0}, o2 = {0,0,0,0}, o3 = {0,0,0,0};
#pragma unroll 8
    for (int k = 0; k < D; ++k) {
        float4 w = *(const float4*)(w1 + k * D + ch * 4);
        int chunk = q ^ ((k >> 3) & 15);
        float4 g = *(const float4*)(gT + k * 64 + chunk * 4);
        o0.x=fmaf(g.x,w.x,o0.x); o0.y=fmaf(g.x,w.y,o0.y); o0.z=fmaf(g.x,w.z,o0.z); o0.w=fmaf(g.x,w.w,o0.w);
        o1.x=fmaf(g.y,w.x,o1.x); o1.y=fmaf(g.y,w.y,o1.y); o1.z=fmaf(g.y,w.z,o1.z); o1.w=fmaf(g.y,w.w,o1.w);
        o2.x=fmaf(g.z,w.x,o2.x); o2.y=fmaf(g.z,w.y,o2.y); o2.z=fmaf(g.z,w.z,o2.z); o2.w=fmaf(g.z,w.w,o2.w);
        o3.x=fmaf(g.w,w.x,o3.x); o3.y=fmaf(g.w,w.y,o3.y); o3.z=fmaf(g.w,w.z,o3.z); o3.w=fmaf(g.w,w.w,o3.w);
    }

    float4 bbv = *(const float4*)(b1 + ch * 4);
    float s[4], qv[4];
#define FIN(i, ov) { \
        ov.x += bbv.x; ov.y += bbv.y; ov.z += bbv.z; ov.w += bbv.w; \
        ov.x = ov.x / (1.f + __expf(-ov.x)); ov.y = ov.y / (1.f + __expf(-ov.y)); \
        ov.z = ov.z / (1.f + __expf(-ov.z)); ov.w = ov.w / (1.f + __expf(-ov.w)); \
        s[i]  = (ov.x + ov.y) + (ov.z + ov.w); \
        qv[i] = fmaf(ov.x, ov.x, fmaf(ov.y, ov.y, fmaf(ov.z, ov.z, ov.w * ov.w))); }
    FIN(0, o0) FIN(1, o1) FIN(2, o2) FIN(3, o3)
#undef FIN

#pragma unroll
    for (int d2 = 1; d2 < 16; d2 <<= 1) {
#pragma unroll
        for (int i = 0; i < 4; ++i) {
            s[i]  += __shfl_xor(s[i],  d2, 64);
            qv[i] += __shfl_xor(qv[i], d2, 64);
        }
    }

#pragma unroll
    for (int i = 0; i < 4; ++i) {
        float mu  = s[i] * (1.f / D);
        float var = qv[i] * (1.f / D) - mu * mu;
        float inv = rsqrtf(var + EPSL);
        int node = base + q * 4 + i;
        if (node < N) {
            float4 ov = (i == 0) ? o0 : (i == 1) ? o1 : (i == 2) ? o2 : o3;
            float4 outv;
            outv.x = (ov.x - mu) * inv;
            outv.y = (ov.y - mu) * inv;
            outv.z = (ov.z - mu) * inv;
            outv.w = (ov.w - mu) * inv;
            *(float4*)(h + (size_t)node * D + ch * 4) = outv;
        }
    }
}

// ---------------- aggregation: h += segment_mean(m[src], dst) ------------------
__global__ __launch_bounds__(256) void k_agg(const float* __restrict__ m,
                                             const int* __restrict__ csr,
                                             const int* __restrict__ off,
                                             float* __restrict__ h, int N)
{
    int g = threadIdx.x >> 4;
    int c = threadIdx.x & 15;
    int node = blockIdx.x * 16 + g;
    if (node >= N) return;

    int b  = off[node];
    int e2 = off[node + 1];
    float4 s0 = {0.f, 0.f, 0.f, 0.f};
    float4 s1 = {0.f, 0.f, 0.f, 0.f};
    int e = b;
    for (; e + 2 <= e2; e += 2) {
        int sn0 = csr[e];
        int sn1 = csr[e + 1];
        float4 v0 = ((const float4*)(m + (size_t)sn0 * D))[c];
        float4 v1 = ((const float4*)(m + (size_t)sn1 * D))[c];
        s0.x += v0.x; s0.y += v0.y; s0.z += v0.z; s0.w += v0.w;
        s1.x += v1.x; s1.y += v1.y; s1.z += v1.z; s1.w += v1.w;
    }
    if (e < e2) {
        int sn = csr[e];
        float4 v = ((const float4*)(m + (size_t)sn * D))[c];
        s0.x += v.x; s0.y += v.y; s0.z += v.z; s0.w += v.w;
    }
    s0.x += s1.x; s0.y += s1.y; s0.z += s1.z; s0.w += s1.w;

    float dnm = fmaxf((float)(e2 - b), 1.f);
    float inv = 1.f / dnm;

    float4* hp = (float4*)(h + (size_t)node * D);
    float4 hv = hp[c];
    hv.x = fmaf(s0.x, inv, hv.x);
    hv.y = fmaf(s0.y, inv, hv.y);
    hv.z = fmaf(s0.z, inv, hv.z);
    hv.w = fmaf(s0.w, inv, hv.w);
    hp[c] = hv;
}

extern "C" void kernel_launch(void* const* d_in, const int* in_sizes, int n_in,
                              void* d_out, int out_size, void* d_ws, size_t ws_size,
                              hipStream_t stream)
{
    const float* x  = (const float*)d_in[0];
    const int*   ei = (const int*)d_in[1];
    const float* w0 = (const float*)d_in[2];
    const float* b0 = (const float*)d_in[3];
    const float* w1 = (const float*)d_in[4];
    const float* b1 = (const float*)d_in[5];
    const float* wa = (const float*)d_in[6];
    const float* ba = (const float*)d_in[7];
    const float* wb = (const float*)d_in[8];
    const float* bb = (const float*)d_in[9];

    const int N = in_sizes[0] / D_IN;
    const int E = in_sizes[1] / 2;
    const int L = in_sizes[6] / (D * H);

    const int* src = ei;
    const int* dst = ei + E;

    // workspace layout (256B aligned chunks)
    char* ws = (char*)d_ws;
    size_t o = 0;
    auto carve = [&](size_t bytes) -> char* {
        char* p = ws + o;
        o = (o + bytes + 255) & ~(size_t)255;
        return p;
    };
    float* m    = (float*)carve((size_t)N * D * sizeof(float));
    int*   csr  = (int*)  carve((size_t)E * sizeof(int));
    int*   cnt  = (int*)  carve((size_t)N * sizeof(int));
    int*   fill = (int*)  carve((size_t)N * sizeof(int));
    int*   offp = (int*)  carve((size_t)(N + 1) * sizeof(int));
    int*   bsum = (int*)  carve((size_t)1024 * sizeof(int));

    float* h = (float*)d_out;

    const int nb = (N + 63) / 64;
    const int G1 = (N + 255) / 256;

    k_zero<<<(N + 255) / 256, 256, 0, stream>>>(cnt, N);
    k_zero<<<(N + 255) / 256, 256, 0, stream>>>(fill, N);
    k_hist<<<(E + 255) / 256, 256, 0, stream>>>(dst, cnt, E);
    k_scan_blk<<<G1, 256, 0, stream>>>(cnt, offp, bsum, N);
    k_scan_top<<<1, 1024, 0, stream>>>(bsum, G1);
    k_scan_add<<<G1, 256, 0, stream>>>(offp, bsum, N);
    k_fill_x<<<2048, 256, 0, stream>>>(src, dst, offp, fill, csr, E);

    k_init<<<nb, 256, 0, stream>>>(x, w0, b0, w1, b1, h, N);

    for (int l = 0; l < L; ++l) {
        k_mlp<<<nb, 256, 0, stream>>>(h, wa + (size_t)l * D * H,
                                      ba + (size_t)l * H,
                                      wb + (size_t)l * H * D,
                                      bb + (size_t)l * D, m, N);
        k_agg<<<(N + 15) / 16, 256, 0, stream>>>(m, csr, offp, h, N);
    }
}